// Round 5
// baseline (183.886 us; speedup 1.0000x reference)
//
#include <hip/hip_runtime.h>
#include <hip/hip_bf16.h>
#include <stdint.h>

// Problem constants: B=2, T=512, P=8, D=1024, NH=16, NKV=4, HD=64
// Rows (b,p,t): 16*512 = 8192.

typedef __attribute__((ext_vector_type(8))) short bf16x8;
typedef __attribute__((ext_vector_type(4))) float f32x4;
typedef __attribute__((ext_vector_type(16))) float f32x16;
typedef __attribute__((ext_vector_type(4))) unsigned short us4;
typedef __attribute__((ext_vector_type(8))) unsigned short us8;

static __device__ __forceinline__ unsigned short f2bf(float f) {
  unsigned u = __float_as_uint(f);
  u += 0x7fffu + ((u >> 16) & 1u);   // RNE
  return (unsigned short)(u >> 16);
}

static __device__ __forceinline__ us8 pack8(float4 a, float4 b) {
  union { __hip_bfloat162 h[4]; us8 v; } u;
  u.h[0] = __float22bfloat162_rn(make_float2(a.x, a.y));
  u.h[1] = __float22bfloat162_rn(make_float2(a.z, a.w));
  u.h[2] = __float22bfloat162_rn(make_float2(b.x, b.y));
  u.h[3] = __float22bfloat162_rn(make_float2(b.z, b.w));
  return u.v;
}

static __device__ __forceinline__ void ld_lds16(const void* g, void* l) {
  __builtin_amdgcn_global_load_lds(
      (const __attribute__((address_space(1))) void*)g,
      (__attribute__((address_space(3))) void*)l, 16, 0, 0);
}

static __device__ __forceinline__ f32x4 mfma16(bf16x8 a, bf16x8 b, f32x4 c) {
  return __builtin_amdgcn_mfma_f32_16x16x32_bf16(a, b, c, 0, 0, 0);
}
static __device__ __forceinline__ f32x16 mfma32(bf16x8 a, bf16x8 b, f32x16 c) {
  return __builtin_amdgcn_mfma_f32_32x32x16_bf16(a, b, c, 0, 0, 0);
}

// ---- weight transpose: W (C=1024,N) f32 -> Wt (N,1024) bf16 --------------
// 640 blocks: 0..255 Wq, 256..319 Wk, 320..383 Wv, 384..639 Wo
__global__ __launch_bounds__(256) void conv_w(
    const float* __restrict__ Wq, const float* __restrict__ Wk,
    const float* __restrict__ Wv, const float* __restrict__ Wo,
    unsigned short* __restrict__ wqkv, unsigned short* __restrict__ wot) {
  __shared__ float tile[64][65];
  int tb = blockIdx.x, tid = threadIdx.x;
  const float* W; unsigned short* Wt; int N, tc0, tn0;
  if (tb < 256)      { W = Wq; Wt = wqkv;                       N = 1024; tc0 = (tb >> 4) * 64;          tn0 = (tb & 15) * 64; }
  else if (tb < 320) { W = Wk; Wt = wqkv + (size_t)1024 * 1024; N = 256;  tc0 = ((tb - 256) >> 2) * 64;  tn0 = ((tb - 256) & 3) * 64; }
  else if (tb < 384) { W = Wv; Wt = wqkv + (size_t)1280 * 1024; N = 256;  tc0 = ((tb - 320) >> 2) * 64;  tn0 = ((tb - 320) & 3) * 64; }
  else               { W = Wo; Wt = wot;                        N = 1024; tc0 = ((tb - 384) >> 4) * 64;  tn0 = ((tb - 384) & 15) * 64; }
  int tr = tid >> 4, tc = tid & 15;
#pragma unroll
  for (int i = 0; i < 4; ++i) {
    int c = tr + i * 16;
    float4 v = *(const float4*)(W + (size_t)(tc0 + c) * N + tn0 + tc * 4);
    tile[c][tc * 4 + 0] = v.x; tile[c][tc * 4 + 1] = v.y;
    tile[c][tc * 4 + 2] = v.z; tile[c][tc * 4 + 3] = v.w;
  }
  __syncthreads();
#pragma unroll
  for (int i = 0; i < 4; ++i) {
    int n = tr + i * 16;
    us4 o;
    o.x = f2bf(tile[tc * 4 + 0][n]); o.y = f2bf(tile[tc * 4 + 1][n]);
    o.z = f2bf(tile[tc * 4 + 2][n]); o.w = f2bf(tile[tc * 4 + 3][n]);
    *(us4*)(Wt + (size_t)(tn0 + n) * 1024 + tc0 + tc * 4) = o;
  }
}

// ---- 128x128x(K=1024) bf16 GEMM, B^T input, register-pipelined staging ---
// grid = NT*64, bid = tn*64 + tm  =>  bid%8 == tm%8: all tn-blocks sharing
// an A-tile land on one XCD (L2 reuse).
// MODE 0: A read directly from hs (B,T,P,D) fp32, packed to bf16 at ds_write.
//         QKV projection + fused RoPE; Q scaled by 0.125.
//         tn 0..7 -> qb; 8..9 -> kb; 10..11 -> vtb TRANSPOSED ((bp,kvh,d),t)
// MODE 1: A = ao bf16 row-major. O projection -> fp32 out[(b,t,p),col].
template <int NT, int MODE>
__global__ __launch_bounds__(256, 3) void gemm_bt(
    const float* __restrict__ Af, const unsigned short* __restrict__ A,
    const unsigned short* __restrict__ Bt,
    unsigned short* __restrict__ qb, unsigned short* __restrict__ kb,
    unsigned short* __restrict__ vtb, float* __restrict__ out) {
  constexpr int K = 1024;
  __shared__ __align__(16) unsigned short Sm[128 * 128];   // As | Bs, reused as Cs
  unsigned short* As = Sm;
  unsigned short* Bs = Sm + 128 * 64;
  unsigned short* Cs = Sm;

  int tid = threadIdx.x;
  int lane = tid & 63, wid = tid >> 6;
  int quad = lane >> 4, lo = lane & 15;
  int tm = blockIdx.x & 63, tn = blockIdx.x >> 6;   // XCD-locality swizzle
  int wm = (wid >> 1) * 64, wn = (wid & 1) * 64;
  int srow = lane >> 3, schunk = lane & 7;

  f32x4 z = {0.f, 0.f, 0.f, 0.f};
  f32x4 acc[4][4];
  for (int i = 0; i < 4; ++i) for (int j = 0; j < 4; ++j) acc[i][j] = z;

  int cg = schunk ^ srow;
  int rowl = wid * 8 + srow;
  const unsigned short* pb = Bt + ((size_t)(tn * 128) + rowl) * K + cg * 8;
  // LDS dest (bytes): (wid*8 + i*32)*128 + lane*16
  char* dA = (char*)As + (wid * 8) * 128 + lane * 16;
  char* dB = (char*)Bs + (wid * 8) * 128 + lane * 16;

  // MODE 0: A from hs fp32; MODE 1: A bf16 row-major
  const float* pax = nullptr;
  const unsigned short* pa = nullptr;
  if constexpr (MODE == 0) {
    int bp = tm >> 2, tt = tm & 3, b = bp >> 3, p = bp & 7;
    pax = Af + ((size_t)b * 4096 + (size_t)(tt * 128 + rowl) * 8 + p) * 1024 + cg * 8;
  } else {
    pa = A + ((size_t)(tm * 128) + rowl) * K + cg * 8;
  }

  float4 raf[8];
  us8 ra[4], rb[4];
#pragma unroll
  for (int i = 0; i < 4; ++i) {      // prologue: tile k0=0
    if constexpr (MODE == 0) {
      raf[2 * i]     = *(const float4*)(pax + (size_t)i * 32 * 8192);
      raf[2 * i + 1] = *(const float4*)(pax + (size_t)i * 32 * 8192 + 4);
    } else {
      ra[i] = *(const us8*)(pa + (size_t)i * 32 * K);
    }
    rb[i] = *(const us8*)(pb + (size_t)i * 32 * K);
  }

  for (int k0 = 0; k0 < K; k0 += 64) {
    __syncthreads();                 // readers of previous tile done
#pragma unroll
    for (int i = 0; i < 4; ++i) {    // stage regs -> LDS
      if constexpr (MODE == 0) {
        *(us8*)(dA + i * 32 * 128) = pack8(raf[2 * i], raf[2 * i + 1]);
      } else {
        *(us8*)(dA + i * 32 * 128) = ra[i];
      }
      *(us8*)(dB + i * 32 * 128) = rb[i];
    }
    __syncthreads();                 // staged tile visible
    if (k0 + 64 < K) {
#pragma unroll
      for (int i = 0; i < 4; ++i) {  // prefetch next tile; lands under MFMA
        if constexpr (MODE == 0) {
          raf[2 * i]     = *(const float4*)(pax + (size_t)i * 32 * 8192 + k0 + 64);
          raf[2 * i + 1] = *(const float4*)(pax + (size_t)i * 32 * 8192 + k0 + 68);
        } else {
          ra[i] = *(const us8*)(pa + (size_t)i * 32 * K + k0 + 64);
        }
        rb[i] = *(const us8*)(pb + (size_t)i * 32 * K + k0 + 64);
      }
    }
#pragma unroll
    for (int kk = 0; kk < 64; kk += 32) {
      bf16x8 af[4], bb[4];
#pragma unroll
      for (int mi = 0; mi < 4; ++mi) {
        int row = wm + mi * 16 + lo;
        int cgx = (quad + (kk >> 3)) ^ (row & 7);
        af[mi] = *(const bf16x8*)(As + (size_t)row * 64 + cgx * 8);
      }
#pragma unroll
      for (int ni = 0; ni < 4; ++ni) {
        int row = wn + ni * 16 + lo;
        int cgx = (quad + (kk >> 3)) ^ (row & 7);
        bb[ni] = *(const bf16x8*)(Bs + (size_t)row * 64 + cgx * 8);
      }
#pragma unroll
      for (int mi = 0; mi < 4; ++mi)
#pragma unroll
        for (int ni = 0; ni < 4; ++ni)
          acc[mi][ni] = mfma16(af[mi], bb[ni], acc[mi][ni]);
    }
  }

  __syncthreads();   // all waves done reading As/Bs before Cs reuse

  // epilogue: C/D layout col = lane&15, row = quad*4 + reg  [m89/m91]
  if (MODE == 0 && tn < 10) {
    float qscale = (tn < 8) ? 0.125f : 1.0f;   // fold 1/sqrt(HD) into Q
#pragma unroll
    for (int mi = 0; mi < 4; ++mi)
#pragma unroll
      for (int r = 0; r < 4; ++r) {
        int t = (tm * 128 + wm + mi * 16 + quad * 4 + r) & 511;
#pragma unroll
        for (int ni = 0; ni < 2; ++ni) {
          float inv = exp2f((float)(ni * 16 + lo) * -0.41524101186092029f);
          float ang = (float)t * inv;
          float s, c;
          __sincosf(ang, &s, &c);
          float x1 = acc[mi][ni][r], x2 = acc[mi][ni + 2][r];
          acc[mi][ni][r]     = (x1 * c - x2 * s) * qscale;
          acc[mi][ni + 2][r] = (x1 * s + x2 * c) * qscale;
        }
      }
#pragma unroll
    for (int mi = 0; mi < 4; ++mi)
#pragma unroll
      for (int ni = 0; ni < 4; ++ni)
#pragma unroll
        for (int r = 0; r < 4; ++r) {
          int row = wm + mi * 16 + quad * 4 + r;
          int col = wn + ni * 16 + lo;
          int cs = col ^ (((row >> 2) & 3) << 3);
          Cs[row * 128 + cs] = f2bf(acc[mi][ni][r]);
        }
    __syncthreads();
    int tc = tid & 15, ro = tid >> 4;
#pragma unroll
    for (int it = 0; it < 8; ++it) {
      int row = ro + 16 * it;
      int cs = (tc * 8) ^ (((row >> 2) & 3) << 3);
      us8 v = *(const us8*)(Cs + row * 128 + cs);
      size_t grow = (size_t)(tm * 128 + row);
      if (tn < 8) {
        *(us8*)(qb + grow * 1024 + tn * 128 + tc * 8) = v;
      } else {
        *(us8*)(kb + grow * 256 + (tn - 8) * 128 + tc * 8) = v;
      }
    }
  } else {
    for (int mi = 0; mi < 4; ++mi) {
      for (int ni = 0; ni < 4; ++ni) {
        int col = tn * 128 + wn + ni * 16 + lo;
        for (int r = 0; r < 4; ++r) {
          int grow = tm * 128 + wm + mi * 16 + quad * 4 + r;
          float val = acc[mi][ni][r];
          if (MODE == 0) {
            int cc = col - 1280;
            int hh = cc >> 6, dd = cc & 63;
            int bp = grow >> 9, t = grow & 511;
            vtb[(((size_t)(bp * 4 + hh)) * 64 + dd) * 512 + t] = f2bf(val);
          } else {
            int bp = grow >> 9, t = grow & 511;
            int b = bp >> 3, p = bp & 7;
            out[((((size_t)b * 512 + t) * 8 + p) << 10) + col] = val;
          }
        }
      }
    }
  }
}

// ---- attention: transposed-S 32x32x16 MFMA, fixed-max softmax,
//      register-pipelined K/V staging -------------------------------------
__global__ __launch_bounds__(256, 4) void attn(
    const unsigned short* __restrict__ qb, const unsigned short* __restrict__ kb,
    const unsigned short* __restrict__ vtb, unsigned short* __restrict__ ao) {
  __shared__ __align__(16) unsigned short Qs[128 * 64];
  __shared__ __align__(16) unsigned short Ks[64 * 64];
  __shared__ __align__(16) unsigned short Vs[64 * 64];   // V^T: [d][key]

  int tid = threadIdx.x;
  int lane = tid & 63, wid = tid >> 6;
  int lo32 = lane & 31, hl = lane >> 5;
  int qt = blockIdx.x & 3, bph = blockIdx.x >> 2;
  int head = bph & 15, bp = bph >> 4;
  int kvh = head >> 2;
  int t0 = qt * 128;
  int srow = lane >> 3, schunk = lane & 7;

  const unsigned short* qg = qb + ((size_t)(bp * 512 + t0)) * 1024 + head * 64;
  const unsigned short* kg = kb + ((size_t)bp * 512) * 256 + kvh * 64;
  const unsigned short* vg = vtb + ((size_t)(bp * 4 + kvh)) * 64 * 512;

  for (int i = 0; i < 4; ++i) {    // stage Q once: 128 rows x 128B
    int row = wid * 8 + i * 32 + srow;
    int cgq = schunk ^ (row & 7);
    ld_lds16(qg + (size_t)row * 1024 + cgq * 8, (char*)Qs + (wid * 8 + i * 32) * 128);
  }

  int cg = schunk ^ srow;          // row&7 == srow for staging rows
  int row0 = wid * 8 + srow, row1 = row0 + 32;
  char* dK = (char*)Ks + (wid * 8) * 128 + lane * 16;
  char* dV = (char*)Vs + (wid * 8) * 128 + lane * 16;

  us8 rk[2], rv[2];
  rk[0] = *(const us8*)(kg + (size_t)row0 * 256 + cg * 8);
  rk[1] = *(const us8*)(kg + (size_t)row1 * 256 + cg * 8);
  rv[0] = *(const us8*)(vg + (size_t)row0 * 512 + cg * 8);
  rv[1] = *(const us8*)(vg + (size_t)row1 * 512 + cg * 8);

  f32x16 z16 = {0.f};
  f32x16 o0 = z16, o1 = z16;
  float psum = 0.f;
  int qrow = wid * 32 + lo32;

  for (int kt = 0; kt < 512; kt += 64) {
    __syncthreads();
    *(us8*)(dK) = rk[0];  *(us8*)(dK + 32 * 128) = rk[1];
    *(us8*)(dV) = rv[0];  *(us8*)(dV + 32 * 128) = rv[1];
    __syncthreads();
    if (kt + 64 < 512) {             // prefetch next K/V tile under compute
      rk[0] = *(const us8*)(kg + (size_t)(kt + 64 + row0) * 256 + cg * 8);
      rk[1] = *(const us8*)(kg + (size_t)(kt + 64 + row1) * 256 + cg * 8);
      rv[0] = *(const us8*)(vg + (size_t)row0 * 512 + kt + 64 + cg * 8);
      rv[1] = *(const us8*)(vg + (size_t)row1 * 512 + kt + 64 + cg * 8);
    }

    // S^T = K . Q^T over d=64 (4 chunks of K=16)
    f32x16 st0 = z16, st1 = z16;
#pragma unroll
    for (int kkc = 0; kkc < 4; ++kkc) {
      int ch = 2 * kkc + hl;
      bf16x8 qf = *(const bf16x8*)(Qs + (size_t)qrow * 64 + ((ch ^ (qrow & 7)) * 8));
      bf16x8 kf0 = *(const bf16x8*)(Ks + (size_t)lo32 * 64 + ((ch ^ (lo32 & 7)) * 8));
      bf16x8 kf1 = *(const bf16x8*)(Ks + (size_t)(32 + lo32) * 64 + ((ch ^ (lo32 & 7)) * 8));
      st0 = mfma32(kf0, qf, st0);
      st1 = mfma32(kf1, qf, st1);
    }

    // exp (no max subtraction; scale pre-folded into Q), pack, PV
#pragma unroll
    for (int t = 0; t < 2; ++t) {
      const f32x16& stv = t ? st1 : st0;
      unsigned pk[8], xpk[8];
#pragma unroll
      for (int p = 0; p < 8; ++p) {
        float e0 = __expf(stv[2 * p]);
        float e1 = __expf(stv[2 * p + 1]);
        psum += e0 + e1;
        pk[p] = ((__float_as_uint(e0) + 0x8000u) >> 16) |
                ((__float_as_uint(e1) + 0x8000u) & 0xffff0000u);
      }
#pragma unroll
      for (int p = 0; p < 8; ++p) xpk[p] = (unsigned)__shfl_xor((int)pk[p], 32);
#pragma unroll
      for (int cc = 0; cc < 2; ++cc) {
        int o = cc * 4;
        union { unsigned u[4]; bf16x8 v; } af;
        if (hl == 0) {
          af.u[0] = pk[o];      af.u[1] = pk[o + 1];
          af.u[2] = xpk[o];     af.u[3] = xpk[o + 1];
        } else {
          af.u[0] = xpk[o + 2]; af.u[1] = xpk[o + 3];
          af.u[2] = pk[o + 2];  af.u[3] = pk[o + 3];
        }
        int vch = 2 * (t * 2 + cc) + hl;
        bf16x8 v0 = *(const bf16x8*)(Vs + (size_t)lo32 * 64 + ((vch ^ (lo32 & 7)) * 8));
        bf16x8 v1 = *(const bf16x8*)(Vs + (size_t)(32 + lo32) * 64 + ((vch ^ (lo32 & 7)) * 8));
        o0 = mfma32(af.v, v0, o0);
        o1 = mfma32(af.v, v1, o1);
      }
    }
  }

  // normalize and store: D layout col=lane&31=d, row q_r=(r&3)+8*(r>>2)+4*hl
  psum += __shfl_xor(psum, 32);
  float inv = 1.f / psum;          // lane holds inv for q = lo32
#pragma unroll
  for (int r = 0; r < 16; ++r) {
    int q_r = (r & 3) + 8 * (r >> 2) + 4 * hl;
    float sc = __shfl(inv, q_r);   // holder lane q_r (lo32=q_r)
    size_t grow = (size_t)(bp * 512 + t0 + wid * 32 + q_r);
    ao[grow * 1024 + head * 64 + lo32]      = f2bf(o0[r] * sc);
    ao[grow * 1024 + head * 64 + 32 + lo32] = f2bf(o1[r] * sc);
  }
}

extern "C" void kernel_launch(void* const* d_in, const int* in_sizes, int n_in,
                              void* d_out, int out_size, void* d_ws, size_t ws_size,
                              hipStream_t stream) {
  const float* hs = (const float*)d_in[0];
  const float* Wq = (const float*)d_in[1];
  const float* Wk = (const float*)d_in[2];
  const float* Wv = (const float*)d_in[3];
  const float* Wo = (const float*)d_in[4];
  float* out = (float*)d_out;

  unsigned short* wqkv = (unsigned short*)d_ws;                 // 1536*1024
  unsigned short* wot  = wqkv + (size_t)1536 * 1024;            // 1024*1024
  unsigned short* qbuf = wot + (size_t)1024 * 1024;             // 8192*1024
  unsigned short* kbuf = qbuf + (size_t)8192 * 1024;            // 8192*256
  unsigned short* vtb  = kbuf + (size_t)8192 * 256;             // 8192*256
  unsigned short* ao   = vtb + (size_t)8192 * 256;              // 8192*1024

  conv_w<<<640, 256, 0, stream>>>(Wq, Wk, Wv, Wo, wqkv, wot);
  gemm_bt<12, 0><<<768, 256, 0, stream>>>(hs, nullptr, wqkv, qbuf, kbuf, vtb, nullptr);
  attn<<<1024, 256, 0, stream>>>(qbuf, kbuf, vtb, ao);
  gemm_bt<8, 1><<<512, 256, 0, stream>>>(nullptr, ao, wot, nullptr, nullptr, nullptr, out);
}